// Round 5
// baseline (5164.208 us; speedup 1.0000x reference)
//
#include <hip/hip_runtime.h>
#include <hip/hip_bf16.h>

#define NB 256
#define TT 128
#define DD 1024
#define HH 1024
#define FH 4096
#define KTOT 3072

typedef __attribute__((ext_vector_type(4))) float f32x4;
typedef __attribute__((ext_vector_type(8))) short short8;

__device__ __forceinline__ unsigned short f2bf(float f) {
    union { float f; unsigned u; } v; v.f = f;
    unsigned u = v.u;
    u += 0x7FFFu + ((u >> 16) & 1u);   // RNE
    return (unsigned short)(u >> 16);
}
__device__ __forceinline__ float bf2f(unsigned short u) {
    union { unsigned u; float f; } v; v.u = ((unsigned)u) << 16; return v.f;
}
__device__ __forceinline__ float sigm(float v) { return 1.f / (1.f + __expf(-v)); }
__device__ __forceinline__ float tanhf_(float v) { return 1.f - 2.f / (__expf(2.f * v) + 1.f); }

__device__ __forceinline__ void bmap(int bid, int& m0, int& j0) {
    int xx = bid & 7, yy = (bid >> 3) & 7, mt = bid >> 6;
    m0 = mt * 64;
    j0 = (xx * 8 + yy) * 16;           // XCD-aligned j tiles
}

__device__ __forceinline__ short8 pack8(float4 v0, float4 v1) {
    short8 r;
    r[0] = (short)f2bf(v0.x); r[1] = (short)f2bf(v0.y);
    r[2] = (short)f2bf(v0.z); r[3] = (short)f2bf(v0.w);
    r[4] = (short)f2bf(v1.x); r[5] = (short)f2bf(v1.y);
    r[6] = (short)f2bf(v1.z); r[7] = (short)f2bf(v1.w);
    return r;
}

// ---------------------------------------------------------------------------
// Wt[c][k] bf16: c = gate*1024+j (4096), k = concat(x:0..1023, h:1024..2047,
// attn-weight rows 2048..3071 used only by the G precompute)
// ---------------------------------------------------------------------------
__global__ __launch_bounds__(256) void wt_prep(const float* __restrict__ Wx,
                                               const float* __restrict__ Wh,
                                               const float* __restrict__ Wattn,
                                               unsigned short* __restrict__ Wt) {
    __shared__ unsigned short tile[64][65];
    int k0 = blockIdx.x * 64;   // 48
    int c0 = blockIdx.y * 64;   // 64
    const float* src; int kl0;
    if (k0 < 1024)      { src = Wx;    kl0 = k0; }
    else if (k0 < 2048) { src = Wh;    kl0 = k0 - 1024; }
    else                { src = Wattn; kl0 = k0 - 2048; }
    int tid = threadIdx.x;
    int r = tid >> 2;
    int ch = (tid & 3) << 4;
    const float* p = src + (size_t)(kl0 + r) * FH + c0 + ch;
#pragma unroll
    for (int i = 0; i < 16; i += 4) {
        float4 v = *reinterpret_cast<const float4*>(p + i);
        tile[r][ch + i + 0] = f2bf(v.x);
        tile[r][ch + i + 1] = f2bf(v.y);
        tile[r][ch + i + 2] = f2bf(v.z);
        tile[r][ch + i + 3] = f2bf(v.w);
    }
    __syncthreads();
    alignas(16) unsigned short vals[16];
#pragma unroll
    for (int i = 0; i < 16; ++i) vals[i] = tile[ch + i][r];
    unsigned short* q = Wt + (size_t)(c0 + r) * KTOT + k0 + ch;
    *reinterpret_cast<uint4*>(q)     = *reinterpret_cast<uint4*>(&vals[0]);
    *reinterpret_cast<uint4*>(q + 8) = *reinterpret_cast<uint4*>(&vals[8]);
}

__global__ __launch_bounds__(256) void zero_buf(float* __restrict__ p, int n) {
    int i = blockIdx.x * 256 + threadIdx.x;
    if (i < n) p[i] = 0.f;
}

// x (fp32) -> xbf (bf16), same [n][t][d] layout
__global__ __launch_bounds__(256) void xconv(const float* __restrict__ x,
                                             unsigned short* __restrict__ xbf) {
    size_t i = ((size_t)blockIdx.x * 256 + threadIdx.x) * 8;
    float4 v0 = *reinterpret_cast<const float4*>(x + i);
    float4 v1 = *reinterpret_cast<const float4*>(x + i + 4);
    short8 p = pack8(v0, v1);
    *reinterpret_cast<short8*>(xbf + i) = p;
}

// AfT[n][l][h] = bf16(A[n][h][l])  == GEMM A matrix, row = n*16+l
__global__ __launch_bounds__(256) void afT_prep(const float* __restrict__ A,
                                                unsigned short* __restrict__ AfT) {
    int n = blockIdx.x;
#pragma unroll
    for (int pass = 0; pass < 4; ++pass) {
        int hh = pass * 256 + threadIdx.x;
        const float4* p = reinterpret_cast<const float4*>(A + ((size_t)n * HH + hh) * 16);
        float4 a0 = p[0], a1 = p[1], a2 = p[2], a3 = p[3];
        float av[16] = {a0.x,a0.y,a0.z,a0.w, a1.x,a1.y,a1.z,a1.w,
                        a2.x,a2.y,a2.z,a2.w, a3.x,a3.y,a3.z,a3.w};
#pragma unroll
        for (int l = 0; l < 16; ++l)
            AfT[((size_t)n * 16 + l) * HH + hh] = f2bf(av[l]);
    }
}

// ---------------------------------------------------------------------------
// G precompute as ONE GEMM: Gflat[row=n*16+l][c] = sum_h AfT[row][h]*Wattn[h][c]
// block 128x128, 4 waves (2m x 2n), wave 64x64 = 4x4 frags, K=1024.
// Deep MLP: 8 independent loads + 16 MFMA chains per K-chunk.
// Output stored as G[n][c][l] (l contiguous) for the epilogue's 32B reads.
// ---------------------------------------------------------------------------
__global__ __launch_bounds__(256) void g_gemm(const unsigned short* __restrict__ AfT,
                                              const unsigned short* __restrict__ Wt,
                                              unsigned short* __restrict__ G) {
    int mt = blockIdx.y;               // 0..31
    int ct = blockIdx.x;               // 0..31
    int tid = threadIdx.x;
    int w = tid >> 6, lane = tid & 63;
    int wm = w >> 1, wn = w & 1;
    int cw = lane & 15, k8 = (lane >> 4) << 3;

    const unsigned short* ap[4];
    const unsigned short* bp[4];
#pragma unroll
    for (int mf = 0; mf < 4; ++mf)
        ap[mf] = AfT + (size_t)(mt * 128 + wm * 64 + mf * 16 + cw) * HH + k8;
#pragma unroll
    for (int fn = 0; fn < 4; ++fn)
        bp[fn] = Wt + (size_t)(ct * 128 + wn * 64 + fn * 16 + cw) * KTOT + 2048 + k8;

    f32x4 acc[4][4];
#pragma unroll
    for (int mf = 0; mf < 4; ++mf)
#pragma unroll
        for (int fn = 0; fn < 4; ++fn)
#pragma unroll
            for (int e = 0; e < 4; ++e) acc[mf][fn][e] = 0.f;

#pragma unroll 4
    for (int ch = 0; ch < 32; ++ch) {
        short8 a[4], b[4];
#pragma unroll
        for (int i = 0; i < 4; ++i)
            a[i] = *reinterpret_cast<const short8*>(ap[i] + ch * 32);
#pragma unroll
        for (int i = 0; i < 4; ++i)
            b[i] = *reinterpret_cast<const short8*>(bp[i] + ch * 32);
#pragma unroll
        for (int mf = 0; mf < 4; ++mf)
#pragma unroll
            for (int fn = 0; fn < 4; ++fn)
                acc[mf][fn] = __builtin_amdgcn_mfma_f32_16x16x32_bf16(
                    a[mf], b[fn], acc[mf][fn], 0, 0, 0);
    }

    int l0 = (lane >> 4) << 2;         // C/D row within frag = l
#pragma unroll
    for (int mf = 0; mf < 4; ++mf) {
        int n = mt * 8 + wm * 4 + mf;  // frag covers exactly one n (16 l's)
#pragma unroll
        for (int fn = 0; fn < 4; ++fn) {
            int cc = ct * 128 + wn * 64 + fn * 16 + cw;
            unsigned lo = (unsigned)f2bf(acc[mf][fn][0]) | ((unsigned)f2bf(acc[mf][fn][1]) << 16);
            unsigned hi = (unsigned)f2bf(acc[mf][fn][2]) | ((unsigned)f2bf(acc[mf][fn][3]) << 16);
            uint2 val; val.x = lo; val.y = hi;
            *reinterpret_cast<uint2*>(G + ((size_t)n * FH + cc) * 16 + l0) = val;
        }
    }
}

// ---------------------------------------------------------------------------
// init: h0 = c0 = mean(Af[n,h,:]); h0 bf16; logits(h0) -> lg0
// ---------------------------------------------------------------------------
__global__ __launch_bounds__(512) void init_kernel(const float* __restrict__ A,
                                                   float* __restrict__ c,
                                                   unsigned short* __restrict__ h0,
                                                   float* __restrict__ lg0) {
    int m0, j0; bmap(blockIdx.x, m0, j0);
    int tid = threadIdx.x;
    int r = tid >> 3, j2 = (tid & 7) * 2;
    int n = m0 + r;
    float lg[16];
#pragma unroll
    for (int l = 0; l < 16; ++l) lg[l] = 0.f;
#pragma unroll
    for (int e = 0; e < 2; ++e) {
        int j = j0 + j2 + e;
        const float4* p = reinterpret_cast<const float4*>(A + ((size_t)n * HH + j) * 16);
        float4 a0 = p[0], a1 = p[1], a2 = p[2], a3 = p[3];
        float av[16] = {a0.x,a0.y,a0.z,a0.w, a1.x,a1.y,a1.z,a1.w,
                        a2.x,a2.y,a2.z,a2.w, a3.x,a3.y,a3.z,a3.w};
        float s = 0.f;
#pragma unroll
        for (int l = 0; l < 16; ++l) s += av[l];
        float m = s * 0.0625f;
        c[(size_t)n * HH + j] = m;
        h0[(size_t)n * HH + j] = f2bf(m);
#pragma unroll
        for (int l = 0; l < 16; ++l) lg[l] += m * av[l];
    }
#pragma unroll
    for (int l = 0; l < 16; ++l) {
        lg[l] += __shfl_xor(lg[l], 1);
        lg[l] += __shfl_xor(lg[l], 2);
        lg[l] += __shfl_xor(lg[l], 4);
    }
    int l0 = (tid & 7) * 2;
    atomicAdd(&lg0[(size_t)n * 16 + l0],     lg[l0]);
    atomicAdd(&lg0[(size_t)n * 16 + l0 + 1], lg[l0 + 1]);
}

// ---------------------------------------------------------------------------
// Per-step fused kernel. Block: 64 rows x 64 cols (4 gates x 16 j), 1024 thr.
// 16 waves = 2m x 2n x 4k; wave tile 32r x 32c, K-quarter 512.
// Quarters 0,1 = x (global); 2,3 = h (global, L2-resident). No staging LDS;
// LDS only for the 4-way k-partial reduce (red[4][col][row], 68KB).
// Epilogue: softmax(lgcur) + w.G fold + bias + LSTM + h/out/c + lg(t+1) atomics.
// ---------------------------------------------------------------------------
template<bool XBF>
__global__ __launch_bounds__(1024)
void gemm_step(const float* __restrict__ x, const unsigned short* __restrict__ xbf,
               const unsigned short* __restrict__ hprev, unsigned short* __restrict__ hnext,
               const unsigned short* __restrict__ Wt, const unsigned short* __restrict__ G,
               const float* __restrict__ A, const float* __restrict__ bb,
               const float* __restrict__ lgcur, float* __restrict__ lgnext,
               float* __restrict__ lgz, float* __restrict__ c,
               float* __restrict__ out, int t) {
    __shared__ float red[2][64][68];   // [partial pair][col][row] 34816 floats
    int m0, j0; bmap(blockIdx.x, m0, j0);
    int tid = threadIdx.x;
    int w = tid >> 6, lane = tid & 63;
    int wk = w & 3, wn = (w >> 2) & 1, wm = w >> 3;
    int cw = lane & 15, k8 = (lane >> 4) << 3;

    f32x4 acc[2][2];
#pragma unroll
    for (int mf = 0; mf < 2; ++mf)
#pragma unroll
        for (int fn = 0; fn < 2; ++fn)
#pragma unroll
            for (int e = 0; e < 4; ++e) acc[mf][fn][e] = 0.f;

    const unsigned short* bp[2];
    int kbase = (wk < 2) ? wk * 512 : 1024 + (wk - 2) * 512;
#pragma unroll
    for (int fn = 0; fn < 2; ++fn) {
        int col = wn * 32 + fn * 16 + cw;
        int brow = (col >> 4) * 1024 + j0 + (col & 15);
        bp[fn] = Wt + (size_t)brow * KTOT + kbase + k8;
    }

    if (wk < 2) {                      // x region
        if (XBF) {
            const unsigned short* ap[2];
#pragma unroll
            for (int mf = 0; mf < 2; ++mf)
                ap[mf] = xbf + ((size_t)(m0 + wm * 32 + mf * 16 + cw) * TT + t) * DD
                             + wk * 512 + k8;
#pragma unroll 4
            for (int ch = 0; ch < 16; ++ch) {
                short8 a0 = *reinterpret_cast<const short8*>(ap[0] + ch * 32);
                short8 a1 = *reinterpret_cast<const short8*>(ap[1] + ch * 32);
                short8 b0 = *reinterpret_cast<const short8*>(bp[0] + ch * 32);
                short8 b1 = *reinterpret_cast<const short8*>(bp[1] + ch * 32);
                acc[0][0] = __builtin_amdgcn_mfma_f32_16x16x32_bf16(a0, b0, acc[0][0], 0, 0, 0);
                acc[0][1] = __builtin_amdgcn_mfma_f32_16x16x32_bf16(a0, b1, acc[0][1], 0, 0, 0);
                acc[1][0] = __builtin_amdgcn_mfma_f32_16x16x32_bf16(a1, b0, acc[1][0], 0, 0, 0);
                acc[1][1] = __builtin_amdgcn_mfma_f32_16x16x32_bf16(a1, b1, acc[1][1], 0, 0, 0);
            }
        } else {
            const float* ap[2];
#pragma unroll
            for (int mf = 0; mf < 2; ++mf)
                ap[mf] = x + ((size_t)(m0 + wm * 32 + mf * 16 + cw) * TT + t) * DD
                           + wk * 512 + k8;
#pragma unroll 2
            for (int ch = 0; ch < 16; ++ch) {
                float4 u0 = *reinterpret_cast<const float4*>(ap[0] + ch * 32);
                float4 u1 = *reinterpret_cast<const float4*>(ap[0] + ch * 32 + 4);
                float4 v0 = *reinterpret_cast<const float4*>(ap[1] + ch * 32);
                float4 v1 = *reinterpret_cast<const float4*>(ap[1] + ch * 32 + 4);
                short8 a0 = pack8(u0, u1);
                short8 a1 = pack8(v0, v1);
                short8 b0 = *reinterpret_cast<const short8*>(bp[0] + ch * 32);
                short8 b1 = *reinterpret_cast<const short8*>(bp[1] + ch * 32);
                acc[0][0] = __builtin_amdgcn_mfma_f32_16x16x32_bf16(a0, b0, acc[0][0], 0, 0, 0);
                acc[0][1] = __builtin_amdgcn_mfma_f32_16x16x32_bf16(a0, b1, acc[0][1], 0, 0, 0);
                acc[1][0] = __builtin_amdgcn_mfma_f32_16x16x32_bf16(a1, b0, acc[1][0], 0, 0, 0);
                acc[1][1] = __builtin_amdgcn_mfma_f32_16x16x32_bf16(a1, b1, acc[1][1], 0, 0, 0);
            }
        }
    } else {                           // h region (global, L2-resident)
        const unsigned short* ap[2];
#pragma unroll
        for (int mf = 0; mf < 2; ++mf)
            ap[mf] = hprev + (size_t)(m0 + wm * 32 + mf * 16 + cw) * HH
                          + (wk - 2) * 512 + k8;
#pragma unroll 4
        for (int ch = 0; ch < 16; ++ch) {
            short8 a0 = *reinterpret_cast<const short8*>(ap[0] + ch * 32);
            short8 a1 = *reinterpret_cast<const short8*>(ap[1] + ch * 32);
            short8 b0 = *reinterpret_cast<const short8*>(bp[0] + ch * 32);
            short8 b1 = *reinterpret_cast<const short8*>(bp[1] + ch * 32);
            acc[0][0] = __builtin_amdgcn_mfma_f32_16x16x32_bf16(a0, b0, acc[0][0], 0, 0, 0);
            acc[0][1] = __builtin_amdgcn_mfma_f32_16x16x32_bf16(a0, b1, acc[0][1], 0, 0, 0);
            acc[1][0] = __builtin_amdgcn_mfma_f32_16x16x32_bf16(a1, b0, acc[1][0], 0, 0, 0);
            acc[1][1] = __builtin_amdgcn_mfma_f32_16x16x32_bf16(a1, b1, acc[1][1], 0, 0, 0);
        }
    }

    // ---- k-partial reduce: wk0/1 write red[0/1]; wk2/3 add into red[0/1] ----
    int r0 = (lane >> 4) << 2;
    if (wk < 2) {
#pragma unroll
        for (int mf = 0; mf < 2; ++mf)
#pragma unroll
            for (int fn = 0; fn < 2; ++fn)
                *reinterpret_cast<f32x4*>(
                    &red[wk][wn * 32 + fn * 16 + cw][wm * 32 + mf * 16 + r0]) = acc[mf][fn];
    }
    __syncthreads();
    if (wk >= 2) {
#pragma unroll
        for (int mf = 0; mf < 2; ++mf)
#pragma unroll
            for (int fn = 0; fn < 2; ++fn) {
                float* p = &red[wk - 2][wn * 32 + fn * 16 + cw][wm * 32 + mf * 16 + r0];
                f32x4 v = *reinterpret_cast<const f32x4*>(p);
                v += acc[mf][fn];
                *reinterpret_cast<f32x4*>(p) = v;
            }
    }
    __syncthreads();

    // ---- epilogue: thread = (row r, col j1) ----
    int r = tid >> 4, j1 = tid & 15;
    int n = m0 + r;
    int j = j0 + j1;

    float sm[16];
    {
        const float4* lp = reinterpret_cast<const float4*>(lgcur + (size_t)n * 16);
        float4 s0 = lp[0], s1 = lp[1], s2 = lp[2], s3 = lp[3];
        float s[16] = {s0.x,s0.y,s0.z,s0.w, s1.x,s1.y,s1.z,s1.w,
                       s2.x,s2.y,s2.z,s2.w, s3.x,s3.y,s3.z,s3.w};
        float mx = -1e30f;
#pragma unroll
        for (int l = 0; l < 16; ++l) { s[l] *= 0.03125f; mx = fmaxf(mx, s[l]); }
        float sum = 0.f;
#pragma unroll
        for (int l = 0; l < 16; ++l) { sm[l] = __expf(s[l] - mx); sum += sm[l]; }
        float inv = 1.f / sum;
#pragma unroll
        for (int l = 0; l < 16; ++l) sm[l] *= inv;
    }

    float pre[4];
#pragma unroll
    for (int g = 0; g < 4; ++g) {
        int colL = g * 16 + j1;
        float p = red[0][colL][r] + red[1][colL][r] + bb[g * HH + j];
        const unsigned short* gp = G + ((size_t)n * FH + g * HH + j) * 16;
        uint4 g0 = *reinterpret_cast<const uint4*>(gp);
        uint4 g1 = *reinterpret_cast<const uint4*>(gp + 8);
        const unsigned* gu = reinterpret_cast<const unsigned*>(&g0);
        const unsigned* gv = reinterpret_cast<const unsigned*>(&g1);
        float d = 0.f;
#pragma unroll
        for (int q = 0; q < 4; ++q) {
            d += sm[q * 2]     * bf2f((unsigned short)(gu[q] & 0xFFFF));
            d += sm[q * 2 + 1] * bf2f((unsigned short)(gu[q] >> 16));
        }
#pragma unroll
        for (int q = 0; q < 4; ++q) {
            d += sm[8 + q * 2]     * bf2f((unsigned short)(gv[q] & 0xFFFF));
            d += sm[8 + q * 2 + 1] * bf2f((unsigned short)(gv[q] >> 16));
        }
        pre[g] = p + d;
    }

    float cv = c[(size_t)n * HH + j];
    float ig = sigm(pre[0]);
    float fg = sigm(pre[1]);
    float og = sigm(pre[2]);
    float gg = tanhf_(pre[3]);
    float cn = fg * cv + ig * gg;
    float hn = og * tanhf_(cn);
    c[(size_t)n * HH + j] = cn;
    hnext[(size_t)n * HH + j] = f2bf(hn);
    out[((size_t)n * TT + t) * HH + j] = hn;

    if ((blockIdx.x & 63) == 0)        // one block per m-tile zeroes lg(t+2)
        lgz[(size_t)n * 16 + j1] = 0.f;

    // next-step logit partials: lg[l] += hn * Af[n][j][l], reduce over 16 j's
    float lg[16];
    {
        const float4* p = reinterpret_cast<const float4*>(A + ((size_t)n * HH + j) * 16);
        float4 a0 = p[0], a1 = p[1], a2 = p[2], a3 = p[3];
        lg[0]=hn*a0.x;  lg[1]=hn*a0.y;  lg[2]=hn*a0.z;  lg[3]=hn*a0.w;
        lg[4]=hn*a1.x;  lg[5]=hn*a1.y;  lg[6]=hn*a1.z;  lg[7]=hn*a1.w;
        lg[8]=hn*a2.x;  lg[9]=hn*a2.y;  lg[10]=hn*a2.z; lg[11]=hn*a2.w;
        lg[12]=hn*a3.x; lg[13]=hn*a3.y; lg[14]=hn*a3.z; lg[15]=hn*a3.w;
    }
#pragma unroll
    for (int l = 0; l < 16; ++l) {
        lg[l] += __shfl_xor(lg[l], 1);
        lg[l] += __shfl_xor(lg[l], 2);
        lg[l] += __shfl_xor(lg[l], 4);
        lg[l] += __shfl_xor(lg[l], 8);
    }
    atomicAdd(&lgnext[(size_t)n * 16 + j1], lg[j1]);
}

// ---------------------------------------------------------------------------
extern "C" void kernel_launch(void* const* d_in, const int* in_sizes, int n_in,
                              void* d_out, int out_size, void* d_ws, size_t ws_size,
                              hipStream_t stream) {
    const float* x     = (const float*)d_in[0];
    const float* A     = (const float*)d_in[1];
    const float* Wx    = (const float*)d_in[2];
    const float* Wh    = (const float*)d_in[3];
    const float* Wattn = (const float*)d_in[4];
    const float* b     = (const float*)d_in[5];
    float* out = (float*)d_out;

    char* ws = (char*)d_ws;
    unsigned short* Wt   = (unsigned short*)(ws);              // 25,165,824
    unsigned short* G    = (unsigned short*)(ws + 25165824);   // 33,554,432
    unsigned short* AfT  = (unsigned short*)(ws + 58720256);   //  8,388,608
    unsigned short* hbuf = (unsigned short*)(ws + 67108864);   //  1,048,576 (2 slots)
    float* c             = (float*)(ws + 68157440);            //  1,048,576
    float* lg            = (float*)(ws + 69206016);            //     49,152 (3 bufs)
    unsigned short* xbf  = (unsigned short*)(ws + 69255168);   // 67,108,864 (optional)
    bool use_xbf = ws_size >= (size_t)69255168 + 67108864;

    wt_prep<<<dim3(48, 64), 256, 0, stream>>>(Wx, Wh, Wattn, Wt);
    zero_buf<<<48, 256, 0, stream>>>(lg, 3 * NB * 16);
    afT_prep<<<NB, 256, 0, stream>>>(A, AfT);
    g_gemm<<<dim3(32, 32), 256, 0, stream>>>(AfT, Wt, G);
    init_kernel<<<256, 512, 0, stream>>>(A, c, hbuf, lg);
    if (use_xbf) xconv<<<16384, 256, 0, stream>>>(x, xbf);

    for (int t = 0; t < TT; ++t) {
        const unsigned short* hp = hbuf + (size_t)(t & 1) * NB * HH;
        unsigned short* hx       = hbuf + (size_t)((t & 1) ^ 1) * NB * HH;
        float* lgc  = lg + (size_t)(t % 3) * NB * 16;
        float* lgn  = lg + (size_t)((t + 1) % 3) * NB * 16;
        float* lgzz = lg + (size_t)((t + 2) % 3) * NB * 16;
        if (use_xbf)
            gemm_step<true><<<256, 1024, 0, stream>>>(x, xbf, hp, hx, Wt, G, A, b,
                                                      lgc, lgn, lgzz, c, out, t);
        else
            gemm_step<false><<<256, 1024, 0, stream>>>(x, xbf, hp, hx, Wt, G, A, b,
                                                       lgc, lgn, lgzz, c, out, t);
    }
}